// Round 2
// baseline (18.944 us; speedup 1.0000x reference)
//
#include <hip/hip_runtime.h>
#include <hip/hip_bf16.h>

#define DIM 4096

// Grid-stride zero fill, float4 (16B) stores.
__global__ void nka_zero_kernel(float4* __restrict__ out4, size_t n4,
                                float* __restrict__ out_tail, int tail) {
    size_t i = (size_t)blockIdx.x * blockDim.x + threadIdx.x;
    size_t stride = (size_t)gridDim.x * blockDim.x;
    const float4 z = {0.f, 0.f, 0.f, 0.f};
    for (; i < n4; i += stride) out4[i] = z;
    size_t t = (size_t)blockIdx.x * blockDim.x + threadIdx.x;
    if (t < (size_t)tail) out_tail[t] = 0.f;
}

// Scatter the 4096 real diagonal values. After Hermitian symmetrization the
// reference matrix is exactly real-diagonal:
//   - off-diag prime corrections cancel: 0.5*(i*c + conj(i*c)) == 0
//   - prime diag corrections (~1.5e-21) and regularization (~2e-16) are far
//     below float32 resolution
// Inputs arrive as float32 (harness downcasts float64 scalars).
__global__ void nka_diag_kernel(float* __restrict__ out,
                                const float* __restrict__ s_re_p,
                                const float* __restrict__ s_im_p,
                                int interleaved) {
    int k = blockIdx.x * blockDim.x + threadIdx.x;
    if (k >= DIM) return;
    double s_re = (double)s_re_p[0];
    double s_im = (double)s_im_p[0];
    double n   = (double)(k + 1);
    double lnn = log(n);
    double lre = -s_re * lnn;                // Re(log_term)
    double val;
    if (lre > -100.0) {
        // Re(exp(-s*ln n)) = exp(-s_re*ln n) * cos(s_im*ln n)
        val = exp(lre) * cos(s_im * lnn);
    } else {
        val = 1e-100;                        // underflow fallback (real)
    }
    size_t idx = (size_t)k * DIM + k;
    if (interleaved) {
        out[idx * 2] = (float)val;           // real part; imag stays 0
    } else {
        out[idx] = (float)val;
    }
}

extern "C" void kernel_launch(void* const* d_in, const int* in_sizes, int n_in,
                              void* d_out, int out_size, void* d_ws, size_t ws_size,
                              hipStream_t stream) {
    const float* s_re = (const float*)d_in[0];
    const float* s_im = (const float*)d_in[1];
    float* out = (float*)d_out;

    // Zero-fill the whole output every call (harness poisons once, never
    // restores between replays — we must rewrite everything each launch).
    size_t n4   = (size_t)out_size / 4;
    int    tail = (int)((size_t)out_size % 4);
    float* tail_ptr = out + n4 * 4;
    nka_zero_kernel<<<2048, 256, 0, stream>>>((float4*)out, n4, tail_ptr, tail);

    // Diagonal scatter. out_size == 2*DIM*DIM -> interleaved (re,im) floats.
    int interleaved = (out_size >= 2 * DIM * DIM) ? 1 : 0;
    nka_diag_kernel<<<(DIM + 255) / 256, 256, 0, stream>>>(out, s_re, s_im, interleaved);
}

// Round 5
// 16.644 us; speedup vs baseline: 1.1382x; 1.1382x over previous
//
#include <hip/hip_runtime.h>
#include <hip/hip_bf16.h>

#define DIM 4096

typedef float f32x4 __attribute__((ext_vector_type(4)));  // native vec for nt-store

// Fused zero-fill + diagonal scatter, one float4 nontemporal store per chunk.
//
// The reference matrix, after Hermitian symmetrization, is exactly real
// diagonal: off-diag prime corrections cancel (0.5*(i*c + conj(i*c)) == 0);
// prime diag corrections (~1.5e-21) and regularization (~2e-16) are below
// float32 resolution. Output is complex128 viewed as interleaved (re,im)
// float pairs: diagonal real k at flat float index k*(2*DIM+2) = 8194*k.
//
// Chunk membership: k_ceil = ceil(f / stride) is the ONLY candidate k with
// stride*k in [f, f+4) (stride >> 4). NB floor(f/stride) is wrong: it only
// matches when stride*k is 4-aligned (even k for stride=8194) — that bug
// dropped all odd-k entries in round 4.
__global__ void nka_fused_kernel(f32x4* __restrict__ out4, unsigned n4,
                                 float* __restrict__ out_tail, int tail,
                                 const float* __restrict__ s_re_p,
                                 const float* __restrict__ s_im_p,
                                 unsigned diag_stride) {
    double s_re = (double)s_re_p[0];
    double s_im = (double)s_im_p[0];

    unsigned i = blockIdx.x * blockDim.x + threadIdx.x;
    unsigned stride = gridDim.x * blockDim.x;
    for (; i < n4; i += stride) {
        unsigned f = i * 4u;                              // first float index of chunk
        unsigned k = (f + diag_stride - 1u) / diag_stride; // ceil: smallest k, d >= f
        unsigned d = k * diag_stride;                      // diagonal float index
        f32x4 v = {0.f, 0.f, 0.f, 0.f};
        if (d < f + 4u && k < DIM) {                       // d >= f by construction
            double lnn = log((double)(k + 1));
            double lre = -s_re * lnn;
            double val = (lre > -100.0) ? exp(lre) * cos(s_im * lnn) : 1e-100;
            v[d - f] = (float)val;
        }
        __builtin_nontemporal_store(v, &out4[i]);
    }
    unsigned t = blockIdx.x * blockDim.x + threadIdx.x;
    if (t < (unsigned)tail) out_tail[t] = 0.f;  // out_size%4 (0 in practice)
}

extern "C" void kernel_launch(void* const* d_in, const int* in_sizes, int n_in,
                              void* d_out, int out_size, void* d_ws, size_t ws_size,
                              hipStream_t stream) {
    const float* s_re = (const float*)d_in[0];
    const float* s_im = (const float*)d_in[1];
    float* out = (float*)d_out;

    unsigned n4   = (unsigned)((size_t)out_size / 4);
    int      tail = (int)((size_t)out_size % 4);
    float*   tail_ptr = out + (size_t)n4 * 4;

    // interleaved (re,im) if out_size covers complex; else real-only layout
    unsigned diag_stride = (out_size >= 2 * DIM * DIM) ? (2u * DIM + 2u)
                                                       : ((unsigned)DIM + 1u);

    // 2048 blocks x 256 thr: 524288 lanes, 16 chunks/thread, grid-stride.
    nka_fused_kernel<<<2048, 256, 0, stream>>>((f32x4*)out, n4, tail_ptr, tail,
                                               s_re, s_im, diag_stride);
}